// Round 1
// baseline (6670.623 us; speedup 1.0000x reference)
//
#include <hip/hip_runtime.h>
#include <cstdint>
#include <cstddef>

// ---------------- problem constants ----------------
constexpr int cN0 = 100000, cN1 = 200000, cN2 = 100000;
constexpr int cD = 128;
constexpr int cNHE = 20000, cHE = 200000;
constexpr int NTOT = cN0 + cN1 + cN2;          // 400000
constexpr long long CSR_NNZ_TOT = 11000000;    // 3*(0.8+1.6+0.8)M + 2*0.4M + 2*0.3M
constexpr int RP_TOT = 1800013;                // sum(n+1) over 13 matrices
constexpr int CNT_TOT = 1800000;               // sum(n)

// ---------------- static device heap ----------------
constexpr size_t AL(size_t x) { return (x + 255) & ~(size_t)255; }
constexpr size_t OFF_Y0 = 0;
constexpr size_t OFF_Y1 = AL(OFF_Y0 + (size_t)cN0 * 640 * 4);
constexpr size_t OFF_Y2 = AL(OFF_Y1 + (size_t)cN1 * 768 * 4);
constexpr size_t OFF_XA = AL(OFF_Y2 + (size_t)cN2 * 640 * 4);
constexpr size_t OFF_XB = AL(OFF_XA + (size_t)NTOT * cD * 4);
constexpr size_t OFF_CC = AL(OFF_XB + (size_t)NTOT * cD * 4);
constexpr size_t OFF_CV = AL(OFF_CC + (size_t)CSR_NNZ_TOT * 4);
constexpr size_t OFF_RP = AL(OFF_CV + (size_t)CSR_NNZ_TOT * 4);
constexpr size_t OFF_CNT = AL(OFF_RP + (size_t)RP_TOT * 4);
constexpr size_t OFF_BS = AL(OFF_CNT + (size_t)CNT_TOT * 4);
constexpr size_t OFF_BS2 = AL(OFF_BS + (size_t)13 * 256 * 4);
constexpr size_t OFF_PL = AL(OFF_BS2 + (size_t)13 * 256 * 4);
constexpr size_t OFF_M = AL(OFF_PL + (size_t)cNHE * cD * 4);
constexpr size_t HEAPSZ = AL(OFF_M + (size_t)cD * 16 * 4);

__device__ __align__(256) unsigned char g_heap[HEAPSZ];

// ---------------- descriptor structs ----------------
struct BD { const int* rows; const int* cols; const float* vals; int nnz; int n; int cnt_off; int rp_off; int csr_off; };
struct BDs { BD d[13]; };

struct GD { const float* A; const float* Wt; float* C; int n; int ldc; int off; };
struct GDs { GD d[16]; };

struct GT { const int* rp; const int* col; const float* val; const float* y; int ld; int off; };
struct GA { GT t[5]; const float* ys; float* out; int sld; int soff; int nt; int n; };

// ---------------- utility kernels ----------------
__global__ void kzero_i(int* p, int n) {
    for (int i = blockIdx.x * 256 + threadIdx.x; i < n; i += gridDim.x * 256) p[i] = 0;
}

// ---------------- CSR build ----------------
__global__ void khist(BDs bs, int* cnt) {
    BD b = bs.d[blockIdx.y];
    for (int e = blockIdx.x * 256 + threadIdx.x; e < b.nnz; e += gridDim.x * 256)
        atomicAdd(&cnt[b.cnt_off + b.rows[e]], 1);
}

__global__ __launch_bounds__(1024) void kscan1(BDs bs, const int* cnt, int* rp, int* bsum) {
    BD b = bs.d[blockIdx.y];
    if ((int)blockIdx.x * 1024 >= b.n) return;
    int tid = threadIdx.x;
    int i = blockIdx.x * 1024 + tid;
    __shared__ int sh[1024];
    int v = (i < b.n) ? cnt[b.cnt_off + i] : 0;
    sh[tid] = v;
    __syncthreads();
    for (int o = 1; o < 1024; o <<= 1) {
        int t = (tid >= o) ? sh[tid - o] : 0;
        __syncthreads();
        sh[tid] += t;
        __syncthreads();
    }
    if (i < b.n) rp[b.rp_off + 1 + i] = sh[tid];
    if (tid == 1023) bsum[blockIdx.y * 256 + blockIdx.x] = sh[1023];
    if (tid == 0 && blockIdx.x == 0) rp[b.rp_off] = 0;
}

__global__ __launch_bounds__(256) void kscan2(BDs bs, const int* bsum, int* bsum2) {
    BD b = bs.d[blockIdx.y];
    int tid = threadIdx.x;
    int nb = (b.n + 1023) >> 10;
    __shared__ int sh[256];
    int v = (tid < nb) ? bsum[blockIdx.y * 256 + tid] : 0;
    sh[tid] = v;
    __syncthreads();
    for (int o = 1; o < 256; o <<= 1) {
        int t = (tid >= o) ? sh[tid - o] : 0;
        __syncthreads();
        sh[tid] += t;
        __syncthreads();
    }
    bsum2[blockIdx.y * 256 + tid] = sh[tid];
}

__global__ __launch_bounds__(1024) void kscan3(BDs bs, int* rp, const int* bsum2) {
    BD b = bs.d[blockIdx.y];
    int bx = blockIdx.x;
    if (bx == 0) return;
    int i = bx * 1024 + threadIdx.x;
    if (i >= b.n) return;
    rp[b.rp_off + 1 + i] += bsum2[blockIdx.y * 256 + bx - 1];
}

__global__ void kscat(BDs bs, const int* rp, int* cur, int* cc, float* cv) {
    BD b = bs.d[blockIdx.y];
    for (int e = blockIdx.x * 256 + threadIdx.x; e < b.nnz; e += gridDim.x * 256) {
        int r = b.rows[e];
        int pos = rp[b.rp_off + r] + atomicAdd(&cur[b.cnt_off + r], 1);
        cc[b.csr_off + pos] = b.cols[e];
        cv[b.csr_off + pos] = b.vals[e];
    }
}

// ---------------- batched f32 GEMM: C[:,off:off+128] = A[n,128] @ Wt[128,128] ----------------
__global__ __launch_bounds__(256, 2) void kgemm(GDs ds) {
    __shared__ float Al[64][68];
    __shared__ float Wl[64][128];
    const GD d = ds.d[blockIdx.y];
    const int row0 = blockIdx.x * 64;
    if (row0 >= d.n) return;
    const int tid = threadIdx.x;
    const int tx = tid & 15, ty = tid >> 4;
    const int rows = (d.n - row0 < 64) ? (d.n - row0) : 64;

    float4 acc[4][2];
#pragma unroll
    for (int j = 0; j < 4; ++j) { acc[j][0] = make_float4(0, 0, 0, 0); acc[j][1] = make_float4(0, 0, 0, 0); }

    for (int kc = 0; kc < 128; kc += 64) {
        // stage A tile (64 rows x 64 k), coalesced float4
#pragma unroll
        for (int i = 0; i < 4; ++i) {
            int idx = tid + i * 256;
            int r = idx >> 4, q = idx & 15;
            float4 v = make_float4(0, 0, 0, 0);
            if (r < rows) v = *(const float4*)(d.A + (size_t)(row0 + r) * 128 + kc + q * 4);
            *(float4*)&Al[r][q * 4] = v;
        }
        // stage W tile (64 k x 128 c)
#pragma unroll
        for (int i = 0; i < 8; ++i) {
            int idx = tid + i * 256;
            int k = idx >> 5, q = idx & 31;
            *(float4*)&Wl[k][q * 4] = *(const float4*)(d.Wt + (size_t)(kc + k) * 128 + q * 4);
        }
        __syncthreads();
#pragma unroll 2
        for (int k = 0; k < 64; k += 4) {
            float4 av[4];
#pragma unroll
            for (int j = 0; j < 4; ++j) av[j] = *(const float4*)&Al[ty * 4 + j][k];
#pragma unroll
            for (int kk = 0; kk < 4; ++kk) {
                float4 w0 = *(const float4*)&Wl[k + kk][tx * 8];
                float4 w1 = *(const float4*)&Wl[k + kk][tx * 8 + 4];
#pragma unroll
                for (int j = 0; j < 4; ++j) {
                    float a = (kk == 0) ? av[j].x : (kk == 1) ? av[j].y : (kk == 2) ? av[j].z : av[j].w;
                    acc[j][0].x += a * w0.x; acc[j][0].y += a * w0.y; acc[j][0].z += a * w0.z; acc[j][0].w += a * w0.w;
                    acc[j][1].x += a * w1.x; acc[j][1].y += a * w1.y; acc[j][1].z += a * w1.z; acc[j][1].w += a * w1.w;
                }
            }
        }
        __syncthreads();
    }
#pragma unroll
    for (int j = 0; j < 4; ++j) {
        int r = row0 + ty * 4 + j;
        if (r < d.n) {
            float* cp = d.C + (size_t)r * d.ldc + d.off + tx * 8;
            *(float4*)cp = acc[j][0];
            *(float4*)(cp + 4) = acc[j][1];
        }
    }
}

// ---------------- fused CSR gather + sum + tanh ----------------
__global__ __launch_bounds__(256) void kgather(GA a) {
    int wave = threadIdx.x >> 6;
    int lane = threadIdx.x & 63;
    int r = blockIdx.x * 4 + wave;
    if (r >= a.n) return;
    const float* sp = a.ys + (size_t)r * a.sld + a.soff + lane * 2;
    float2 acc = *(const float2*)sp;
    for (int t = 0; t < a.nt; ++t) {
        GT g = a.t[t];
        int e0 = g.rp[r], e1 = g.rp[r + 1];
        const float* yb = g.y + g.off + lane * 2;
        for (int e = e0; e < e1; ++e) {
            int c = g.col[e];
            float v = g.val[e];
            float2 yv = *(const float2*)(yb + (size_t)c * g.ld);
            acc.x += v * yv.x;
            acc.y += v * yv.y;
        }
    }
    float2 o;
    o.x = tanhf(acc.x);
    o.y = tanhf(acc.y);
    *(float2*)(a.out + (size_t)r * 128 + lane * 2) = o;
}

// ---------------- pooling + head ----------------
__device__ inline int lbound(const int* arr, int n, int key) {
    int lo = 0, hi = n;
    while (lo < hi) { int mid = (lo + hi) >> 1; if (arr[mid] < key) lo = mid + 1; else hi = mid; }
    return lo;
}

__global__ __launch_bounds__(128) void kpool(const float* x0, const int* he_idx, const int* he_seg, float* pool) {
    int s = blockIdx.x;
    int t = threadIdx.x;
    int lo = lbound(he_seg, cHE, s);
    int hi = lbound(he_seg, cHE, s + 1);
    float acc = 0.f;
    for (int e = lo; e < hi; ++e) acc += x0[(size_t)he_idx[e] * 128 + t];
    float c = (float)(hi - lo);
    pool[(size_t)s * 128 + t] = acc / fmaxf(c, 1.f);
}

__global__ void kmatm(const float* Wfc, const float* Wcls, float* M) {
    int o = blockIdx.x * 256 + threadIdx.x;
    if (o >= 128 * 16) return;
    int dd = o >> 4, j = o & 15;
    float s = 0.f;
    for (int c = 0; c < 128; ++c) s += Wfc[dd * 128 + c] * Wcls[c * 16 + j];
    M[o] = s;
}

__global__ __launch_bounds__(256) void khead(const float* pool, const float* M, const float* bcls, float* out) {
    int row = blockIdx.x * 16 + (threadIdx.x >> 4);
    int j = threadIdx.x & 15;
    if (row >= cNHE - 1) return;
    int s = row + 1;
    float acc = bcls[j];
    const float* p = pool + (size_t)s * 128;
    for (int dd = 0; dd < 128; ++dd) acc += p[dd] * M[dd * 16 + j];
    out[(size_t)row * 16 + j] = acc;
}

// ---------------- host driver ----------------
extern "C" void kernel_launch(void* const* d_in, const int* in_sizes, int n_in,
                              void* d_out, int out_size, void* d_ws, size_t ws_size,
                              hipStream_t stream) {
    (void)in_sizes; (void)n_in; (void)out_size; (void)d_ws; (void)ws_size;

    unsigned char* heap = nullptr;
    hipGetSymbolAddress((void**)&heap, HIP_SYMBOL(g_heap));

    float* y0 = (float*)(heap + OFF_Y0);
    float* y1 = (float*)(heap + OFF_Y1);
    float* y2 = (float*)(heap + OFF_Y2);
    float* xA = (float*)(heap + OFF_XA);
    float* xB = (float*)(heap + OFF_XB);
    int* cc = (int*)(heap + OFF_CC);
    float* cv = (float*)(heap + OFF_CV);
    int* rp = (int*)(heap + OFF_RP);
    int* cnt = (int*)(heap + OFF_CNT);
    int* bsum = (int*)(heap + OFF_BS);
    int* bsum2 = (int*)(heap + OFF_BS2);
    float* pool = (float*)(heap + OFF_PL);
    float* Mbuf = (float*)(heap + OFF_M);

    const float* X0 = (const float*)d_in[0];
    const float* X1 = (const float*)d_in[1];
    const float* X2 = (const float*)d_in[2];
    const float* Wp = (const float*)d_in[29];

    // --- build matrix descriptors ---
    static const int mnnz[13] = {800000, 800000, 800000, 1600000, 1600000, 1600000,
                                 800000, 800000, 800000, 400000, 400000, 300000, 300000};
    static const int mn[13] = {cN0, cN0, cN0, cN1, cN1, cN1, cN2, cN2, cN2, cN0, cN1, cN1, cN2};

    BDs bs;
    {
        int coff = 0, rpoff = 0, csroff = 0;
        for (int m = 0; m < 13; ++m) {
            BD& b = bs.d[m];
            if (m < 9) {
                const int* p = (const int*)d_in[3 + 2 * m];
                b.rows = p;
                b.cols = p + mnnz[m];
                b.vals = (const float*)d_in[4 + 2 * m];
            } else if (m == 9) { b.rows = (const int*)d_in[21]; b.cols = (const int*)d_in[22]; b.vals = (const float*)d_in[23]; }
            else if (m == 10) { b.rows = (const int*)d_in[22]; b.cols = (const int*)d_in[21]; b.vals = (const float*)d_in[23]; }
            else if (m == 11) { b.rows = (const int*)d_in[24]; b.cols = (const int*)d_in[25]; b.vals = (const float*)d_in[26]; }
            else              { b.rows = (const int*)d_in[25]; b.cols = (const int*)d_in[24]; b.vals = (const float*)d_in[26]; }
            b.nnz = mnnz[m]; b.n = mn[m];
            b.cnt_off = coff; b.rp_off = rpoff; b.csr_off = csroff;
            coff += mn[m]; rpoff += mn[m] + 1; csroff += mnnz[m];
        }
    }

    // --- CSR build ---
    kzero_i<<<dim3(2048), 256, 0, stream>>>(cnt, CNT_TOT);
    khist<<<dim3(1024, 13), 256, 0, stream>>>(bs, cnt);
    kscan1<<<dim3(196, 13), 1024, 0, stream>>>(bs, cnt, rp, bsum);
    kscan2<<<dim3(1, 13), 256, 0, stream>>>(bs, bsum, bsum2);
    kscan3<<<dim3(196, 13), 1024, 0, stream>>>(bs, rp, bsum2);
    kzero_i<<<dim3(2048), 256, 0, stream>>>(cnt, CNT_TOT);
    kscat<<<dim3(1024, 13), 256, 0, stream>>>(bs, rp, cnt, cc, cv);

    auto RP = [&](int m) { return rp + bs.d[m].rp_off; };
    auto CC = [&](int m) { return cc + bs.d[m].csr_off; };
    auto CV = [&](int m) { return cv + bs.d[m].csr_off; };

    // --- 3 layers ---
    for (int l = 0; l < 3; ++l) {
        const float* xi0 = (l == 0) ? X0 : ((l == 1) ? xA : xB);
        const float* xi1 = (l == 0) ? X1 : ((l == 1) ? xA + (size_t)cN0 * 128 : xB + (size_t)cN0 * 128);
        const float* xi2 = (l == 0) ? X2 : ((l == 1) ? xA + (size_t)(cN0 + cN1) * 128 : xB + (size_t)(cN0 + cN1) * 128);
        float* xo = (l == 1) ? xB : xA;

        auto W_ = [&](int s, int t) { return Wp + (size_t)((l * 3 + s) * 6 + t) * 128 * 128; };

        GDs gs;
        int nt = 0;
        if (l < 2) {
            gs.d[nt++] = {xi0, W_(0, 0), y0, cN0, 640, 0};
            gs.d[nt++] = {xi0, W_(0, 1), y0, cN0, 640, 128};
            gs.d[nt++] = {xi0, W_(0, 2), y0, cN0, 640, 256};
            gs.d[nt++] = {xi0, W_(0, 3), y0, cN0, 640, 384};
            gs.d[nt++] = {xi0, W_(1, 4), y0, cN0, 640, 512};
            gs.d[nt++] = {xi1, W_(1, 0), y1, cN1, 768, 0};
            gs.d[nt++] = {xi1, W_(1, 1), y1, cN1, 768, 128};
            gs.d[nt++] = {xi1, W_(1, 2), y1, cN1, 768, 256};
            gs.d[nt++] = {xi1, W_(1, 3), y1, cN1, 768, 384};
            gs.d[nt++] = {xi1, W_(0, 5), y1, cN1, 768, 512};
            gs.d[nt++] = {xi1, W_(2, 4), y1, cN1, 768, 640};
            gs.d[nt++] = {xi2, W_(2, 0), y2, cN2, 640, 0};
            gs.d[nt++] = {xi2, W_(2, 1), y2, cN2, 640, 128};
            gs.d[nt++] = {xi2, W_(2, 2), y2, cN2, 640, 256};
            gs.d[nt++] = {xi2, W_(2, 3), y2, cN2, 640, 384};
            gs.d[nt++] = {xi2, W_(1, 5), y2, cN2, 640, 512};
        } else {
            gs.d[nt++] = {xi0, W_(0, 0), y0, cN0, 640, 0};
            gs.d[nt++] = {xi0, W_(0, 1), y0, cN0, 640, 128};
            gs.d[nt++] = {xi0, W_(0, 2), y0, cN0, 640, 256};
            gs.d[nt++] = {xi0, W_(0, 3), y0, cN0, 640, 384};
            gs.d[nt++] = {xi1, W_(0, 5), y1, cN1, 768, 512};
        }
        kgemm<<<dim3(3125, nt), 256, 0, stream>>>(gs);

        // gather dim0
        {
            GA a{};
            a.nt = 4; a.ys = y0; a.sld = 640; a.soff = 0; a.out = xo; a.n = cN0;
            a.t[0] = {RP(0), CC(0), CV(0), y0, 640, 128};
            a.t[1] = {RP(1), CC(1), CV(1), y0, 640, 256};
            a.t[2] = {RP(2), CC(2), CV(2), y0, 640, 384};
            a.t[3] = {RP(9), CC(9), CV(9), y1, 768, 512};
            kgather<<<dim3((cN0 + 3) / 4), 256, 0, stream>>>(a);
        }
        if (l < 2) {
            GA a{};
            a.nt = 5; a.ys = y1; a.sld = 768; a.soff = 0; a.out = xo + (size_t)cN0 * 128; a.n = cN1;
            a.t[0] = {RP(3), CC(3), CV(3), y1, 768, 128};
            a.t[1] = {RP(4), CC(4), CV(4), y1, 768, 256};
            a.t[2] = {RP(5), CC(5), CV(5), y1, 768, 384};
            a.t[3] = {RP(10), CC(10), CV(10), y0, 640, 512};
            a.t[4] = {RP(11), CC(11), CV(11), y2, 640, 512};
            kgather<<<dim3((cN1 + 3) / 4), 256, 0, stream>>>(a);

            GA a2{};
            a2.nt = 4; a2.ys = y2; a2.sld = 640; a2.soff = 0; a2.out = xo + (size_t)(cN0 + cN1) * 128; a2.n = cN2;
            a2.t[0] = {RP(6), CC(6), CV(6), y2, 640, 128};
            a2.t[1] = {RP(7), CC(7), CV(7), y2, 640, 256};
            a2.t[2] = {RP(8), CC(8), CV(8), y2, 640, 384};
            a2.t[3] = {RP(12), CC(12), CV(12), y1, 768, 640};
            kgather<<<dim3((cN2 + 3) / 4), 256, 0, stream>>>(a2);
        }
    }

    // --- pooling + head ---
    kpool<<<dim3(cNHE), 128, 0, stream>>>(xA, (const int*)d_in[27], (const int*)d_in[28], pool);
    kmatm<<<dim3(8), 256, 0, stream>>>((const float*)d_in[30], (const float*)d_in[31], Mbuf);
    khead<<<dim3((cNHE - 1 + 15) / 16), 256, 0, stream>>>(pool, Mbuf, (const float*)d_in[32], (float*)d_out);
}

// Round 2
// 4716.189 us; speedup vs baseline: 1.4144x; 1.4144x over previous
//
#include <hip/hip_runtime.h>
#include <cstdint>
#include <cstddef>

typedef float f4v __attribute__((ext_vector_type(4)));
typedef __bf16 bf8 __attribute__((ext_vector_type(8)));

// ---------------- problem constants ----------------
constexpr int cN0 = 100000, cN1 = 200000, cN2 = 100000;
constexpr int cNHE = 20000, cHE = 200000;
constexpr int N0p = 100096, N1p = 200064, N2p = 100096;   // padded to 128 rows
constexpr int NTP = N0p + N1p + N2p;
constexpr long long CSR_NNZ_TOT = 11000000;
constexpr int RP_TOT = 1800013;
constexpr int CNT_TOT = 1800000;
constexpr int NWE = 54 * 16384;   // prepped W elements per plane

// ---------------- static device heap ----------------
constexpr size_t AL(size_t x) { return (x + 255) & ~(size_t)255; }
constexpr size_t OFF_XIN = 0;
constexpr size_t OFF_XA  = AL(OFF_XIN + (size_t)NTP * 128 * 2);
constexpr size_t OFF_XB  = AL(OFF_XA  + (size_t)NTP * 128 * 2);
constexpr size_t OFF_Y0  = AL(OFF_XB  + (size_t)NTP * 128 * 2);
constexpr size_t OFF_Y1  = AL(OFF_Y0  + (size_t)N0p * 640 * 2);
constexpr size_t OFF_Y2  = AL(OFF_Y1  + (size_t)N1p * 768 * 2);
constexpr size_t OFF_WHI = AL(OFF_Y2  + (size_t)N2p * 640 * 2);
constexpr size_t OFF_WLO = AL(OFF_WHI + (size_t)NWE * 2);
constexpr size_t OFF_CC  = AL(OFF_WLO + (size_t)NWE * 2);
constexpr size_t OFF_CV  = AL(OFF_CC  + (size_t)CSR_NNZ_TOT * 4);
constexpr size_t OFF_RP  = AL(OFF_CV  + (size_t)CSR_NNZ_TOT * 4);
constexpr size_t OFF_CNT = AL(OFF_RP  + (size_t)RP_TOT * 4);
constexpr size_t OFF_BS  = AL(OFF_CNT + (size_t)CNT_TOT * 4);
constexpr size_t OFF_BS2 = AL(OFF_BS  + (size_t)13 * 256 * 4);
constexpr size_t OFF_PL  = AL(OFF_BS2 + (size_t)13 * 256 * 4);
constexpr size_t OFF_M   = AL(OFF_PL  + (size_t)cNHE * 128 * 4);
constexpr size_t HEAPSZ  = AL(OFF_M   + (size_t)128 * 16 * 4);

__device__ __align__(256) unsigned char g_heap[HEAPSZ];

// ---------------- helpers ----------------
__device__ __forceinline__ ushort f2bf(float f) {
    union { float f; uint32_t u; } v{f};
    uint32_t r = v.u + 0x7fffu + ((v.u >> 16) & 1u);
    return (ushort)(r >> 16);
}
__device__ __forceinline__ float bflo(uint32_t u) { union { uint32_t u; float f; } v{u << 16}; return v.f; }
__device__ __forceinline__ float bfhi(uint32_t u) { union { uint32_t u; float f; } v{u & 0xffff0000u}; return v.f; }

__device__ __forceinline__ void gl_lds16(const ushort* g, ushort* l) {
    __builtin_amdgcn_global_load_lds((const __attribute__((address_space(1))) void*)g,
                                     (__attribute__((address_space(3))) void*)l, 16, 0, 0);
}

// ---------------- descriptor structs ----------------
struct BD { const int* rows; const int* cols; const float* vals; int nnz; int n; int cnt_off; int rp_off; int csr_off; };
struct BDs { BD d[13]; };

struct GG { const ushort* x; ushort* y; int n; int nblk; int bstart; int ldy; int colbase; int nt; int mats[6]; };
struct GGs { GG g[3]; int ng; };

struct GT { const int* rp; const int* col; const float* val; const ushort* y; int ld; int off; };
struct GA { GT t[5]; const ushort* ys; ushort* out; int sld; int soff; int nt; int n; };

// ---------------- utility kernels ----------------
__global__ void kzero_i(int* p, int n) {
    for (int i = blockIdx.x * 256 + threadIdx.x; i < n; i += gridDim.x * 256) p[i] = 0;
}

__global__ void kcvt(const float4* __restrict__ src, uint2* __restrict__ dst, int n4) {
    int i = blockIdx.x * 256 + threadIdx.x;
    if (i >= n4) return;
    float4 v = src[i];
    dst[i] = make_uint2((uint32_t)f2bf(v.x) | ((uint32_t)f2bf(v.y) << 16),
                        (uint32_t)f2bf(v.z) | ((uint32_t)f2bf(v.w) << 16));
}

// W prep: split into hi/lo bf16, arranged for direct 16B fragment loads.
// layout idx = ((kf*8+cf)*64 + lane)*8 + i  -> element (k = kf*32+(lane>>4)*8+i, c = cf*16+(lane&15))
__global__ void kwprep(const float* __restrict__ W, ushort* __restrict__ whi, ushort* __restrict__ wlo) {
    int t = blockIdx.x * 256 + threadIdx.x;
    if (t >= NWE) return;
    int mat = t >> 14, r = t & 16383;
    int i = r & 7, l = (r >> 3) & 63, cf = (r >> 9) & 7, kf = r >> 12;
    int k = kf * 32 + (l >> 4) * 8 + i;
    int c = cf * 16 + (l & 15);
    float w = W[(size_t)mat * 16384 + k * 128 + c];
    ushort h = f2bf(w);
    union { uint32_t u; float f; } hv{(uint32_t)h << 16};
    whi[t] = h;
    wlo[t] = f2bf(w - hv.f);
}

// ---------------- CSR build ----------------
__global__ void khist(BDs bs, int* cnt) {
    BD b = bs.d[blockIdx.y];
    for (int e = blockIdx.x * 256 + threadIdx.x; e < b.nnz; e += gridDim.x * 256)
        atomicAdd(&cnt[b.cnt_off + b.rows[e]], 1);
}

__global__ __launch_bounds__(1024) void kscan1(BDs bs, const int* cnt, int* rp, int* bsum) {
    BD b = bs.d[blockIdx.y];
    if ((int)blockIdx.x * 1024 >= b.n) return;
    int tid = threadIdx.x;
    int i = blockIdx.x * 1024 + tid;
    __shared__ int sh[1024];
    int v = (i < b.n) ? cnt[b.cnt_off + i] : 0;
    sh[tid] = v;
    __syncthreads();
    for (int o = 1; o < 1024; o <<= 1) {
        int t = (tid >= o) ? sh[tid - o] : 0;
        __syncthreads();
        sh[tid] += t;
        __syncthreads();
    }
    if (i < b.n) rp[b.rp_off + 1 + i] = sh[tid];
    if (tid == 1023) bsum[blockIdx.y * 256 + blockIdx.x] = sh[1023];
    if (tid == 0 && blockIdx.x == 0) rp[b.rp_off] = 0;
}

__global__ __launch_bounds__(256) void kscan2(BDs bs, const int* bsum, int* bsum2) {
    BD b = bs.d[blockIdx.y];
    int tid = threadIdx.x;
    int nb = (b.n + 1023) >> 10;
    __shared__ int sh[256];
    int v = (tid < nb) ? bsum[blockIdx.y * 256 + tid] : 0;
    sh[tid] = v;
    __syncthreads();
    for (int o = 1; o < 256; o <<= 1) {
        int t = (tid >= o) ? sh[tid - o] : 0;
        __syncthreads();
        sh[tid] += t;
        __syncthreads();
    }
    bsum2[blockIdx.y * 256 + tid] = sh[tid];
}

__global__ __launch_bounds__(1024) void kscan3(BDs bs, int* rp, const int* bsum2) {
    BD b = bs.d[blockIdx.y];
    int bx = blockIdx.x;
    if (bx == 0) return;
    int i = bx * 1024 + threadIdx.x;
    if (i >= b.n) return;
    rp[b.rp_off + 1 + i] += bsum2[blockIdx.y * 256 + bx - 1];
}

__global__ void kscat(BDs bs, const int* rp, int* cur, int* cc, float* cv) {
    BD b = bs.d[blockIdx.y];
    for (int e = blockIdx.x * 256 + threadIdx.x; e < b.nnz; e += gridDim.x * 256) {
        int r = b.rows[e];
        int pos = rp[b.rp_off + r] + atomicAdd(&cur[b.cnt_off + r], 1);
        cc[b.csr_off + pos] = b.cols[e];
        cv[b.csr_off + pos] = b.vals[e];
    }
}

// ---------------- MFMA GEMM: y[:, colbase + t*128 .. +128] = x @ (Whi+Wlo)[mats[t]] ----------------
__global__ __launch_bounds__(256, 2) void kgemm_mfma(GGs gs, const ushort* __restrict__ whi, const ushort* __restrict__ wlo) {
    __shared__ __align__(16) ushort xt[128 * 128];      // 32 KB, XOR-swizzled 16B slots
    __shared__ __align__(16) ushort st[4 * 32 * 128];   // 32 KB store-stage, 8 KB/wave
    const int bx = blockIdx.x;
    int gi = 0;
#pragma unroll
    for (int i = 1; i < 3; ++i)
        if (i < gs.ng && bx >= gs.g[i].bstart) gi = i;
    const GG g = gs.g[gi];
    const int row0 = (bx - g.bstart) * 128;
    const int tid = threadIdx.x;
    const int lane = tid & 63, wv = tid >> 6;
    const int l15 = lane & 15, hi4 = lane >> 4;

    // stage x tile: LDS linear, global source pre-swizzled (slot ^= row&7)
    {
        const ushort* xb = g.x + (size_t)row0 * 128;
#pragma unroll
        for (int it = 0; it < 8; ++it) {
            int u = (it * 4 + wv) * 64 + lane;          // 16B-unit index 0..2047
            int r = u >> 4, c16 = u & 15;
            gl_lds16(xb + (size_t)r * 128 + ((c16 ^ (r & 7)) * 8), &xt[(it * 4 + wv) * 512]);
        }
    }
    __syncthreads();

    ushort* sb = &st[wv * 4096];

    for (int t = 0; t < g.nt; ++t) {
        const int mat = g.mats[t];
        f4v acc[2][8];
        f4v zz = {0.f, 0.f, 0.f, 0.f};
#pragma unroll
        for (int rf = 0; rf < 2; ++rf)
#pragma unroll
            for (int cf = 0; cf < 8; ++cf) acc[rf][cf] = zz;

#pragma unroll
        for (int h = 0; h < 2; ++h) {
            const ushort* wb = (h ? wlo : whi) + (size_t)mat * 16384;
#pragma unroll
            for (int kf = 0; kf < 4; ++kf) {
                bf8 wf[8];
#pragma unroll
                for (int cf = 0; cf < 8; ++cf)
                    wf[cf] = *(const bf8*)(wb + ((kf * 8 + cf) * 64 + lane) * 8);
                bf8 xf[2];
#pragma unroll
                for (int rf = 0; rf < 2; ++rf) {
                    int rl = wv * 32 + rf * 16 + l15;
                    int slot = (kf * 4 + hi4) ^ (rl & 7);
                    xf[rf] = *(const bf8*)&xt[rl * 128 + slot * 8];
                }
                // D = (W^T tile)·(x^T tile): D-col = x-row = lane&15, D-rows = 4 consecutive W-cols
#pragma unroll
                for (int rf = 0; rf < 2; ++rf)
#pragma unroll
                    for (int cf = 0; cf < 8; ++cf)
                        acc[rf][cf] = __builtin_amdgcn_mfma_f32_16x16x32_bf16(wf[cf], xf[rf], acc[rf][cf], 0, 0, 0);
            }
        }

        __syncthreads();   // prev term's read-back complete before sb overwrite
#pragma unroll
        for (int rf = 0; rf < 2; ++rf) {
#pragma unroll
            for (int cf = 0; cf < 8; ++cf) {
                int rl = rf * 16 + l15;
                uint32_t p0 = (uint32_t)f2bf(acc[rf][cf][0]) | ((uint32_t)f2bf(acc[rf][cf][1]) << 16);
                uint32_t p1 = (uint32_t)f2bf(acc[rf][cf][2]) | ((uint32_t)f2bf(acc[rf][cf][3]) << 16);
                int s0 = cf * 2 + (hi4 >> 1);
                int byteoff = rl * 256 + ((s0 ^ (rl & 7)) * 16) + (hi4 & 1) * 8;
                *(uint2*)((char*)sb + byteoff) = make_uint2(p0, p1);
            }
        }
        __syncthreads();
        ushort* yb = g.y + (size_t)(row0 + wv * 32) * g.ldy + g.colbase + t * 128;
#pragma unroll
        for (int it = 0; it < 8; ++it) {
            int rl = it * 4 + hi4;
            int s = l15 ^ (rl & 7);
            uint4 v = *(const uint4*)((const char*)sb + rl * 256 + s * 16);
            int absrow = row0 + wv * 32 + rl;
            if (absrow < g.n)
                *(uint4*)(yb + (size_t)rl * g.ldy + l15 * 8) = v;
        }
        __syncthreads();
    }
}

// ---------------- fused CSR gather + sum + tanh (bf16 in/out, f32 accum) ----------------
__global__ __launch_bounds__(256) void kgather(GA a) {
    int wv = threadIdx.x >> 6, lane = threadIdx.x & 63;
    int r = blockIdx.x * 4 + wv;
    if (r >= a.n) return;
    uint32_t sv = *(const uint32_t*)(a.ys + (size_t)r * a.sld + a.soff + lane * 2);
    float ax = bflo(sv), ay = bfhi(sv);
    for (int t = 0; t < a.nt; ++t) {
        GT g = a.t[t];
        int e0 = g.rp[r], e1 = g.rp[r + 1];
        const ushort* yb = g.y + g.off + lane * 2;
        for (int e = e0; e < e1; ++e) {
            int c = g.col[e];
            float v = g.val[e];
            uint32_t yv = *(const uint32_t*)(yb + (size_t)c * g.ld);
            ax += v * bflo(yv);
            ay += v * bfhi(yv);
        }
    }
    uint32_t o = (uint32_t)f2bf(tanhf(ax)) | ((uint32_t)f2bf(tanhf(ay)) << 16);
    *(uint32_t*)(a.out + (size_t)r * 128 + lane * 2) = o;
}

// ---------------- pooling + head ----------------
__device__ inline int lbound(const int* arr, int n, int key) {
    int lo = 0, hi = n;
    while (lo < hi) { int mid = (lo + hi) >> 1; if (arr[mid] < key) lo = mid + 1; else hi = mid; }
    return lo;
}

__global__ __launch_bounds__(128) void kpool(const ushort* x0, const int* he_idx, const int* he_seg, float* pool) {
    int s = blockIdx.x;
    int t = threadIdx.x;
    int lo = lbound(he_seg, cHE, s);
    int hi = lbound(he_seg, cHE, s + 1);
    float acc = 0.f;
    for (int e = lo; e < hi; ++e) acc += bflo((uint32_t)x0[(size_t)he_idx[e] * 128 + t]);
    float c = (float)(hi - lo);
    pool[(size_t)s * 128 + t] = acc / fmaxf(c, 1.f);
}

__global__ void kmatm(const float* Wfc, const float* Wcls, float* M) {
    int o = blockIdx.x * 256 + threadIdx.x;
    if (o >= 128 * 16) return;
    int dd = o >> 4, j = o & 15;
    float s = 0.f;
    for (int c = 0; c < 128; ++c) s += Wfc[dd * 128 + c] * Wcls[c * 16 + j];
    M[o] = s;
}

__global__ __launch_bounds__(256) void khead(const float* pool, const float* M, const float* bcls, float* out) {
    int row = blockIdx.x * 16 + (threadIdx.x >> 4);
    int j = threadIdx.x & 15;
    if (row >= cNHE - 1) return;
    int s = row + 1;
    float acc = bcls[j];
    const float* p = pool + (size_t)s * 128;
    for (int dd = 0; dd < 128; ++dd) acc += p[dd] * M[dd * 16 + j];
    out[(size_t)row * 16 + j] = acc;
}

// ---------------- host driver ----------------
extern "C" void kernel_launch(void* const* d_in, const int* in_sizes, int n_in,
                              void* d_out, int out_size, void* d_ws, size_t ws_size,
                              hipStream_t stream) {
    (void)in_sizes; (void)n_in; (void)out_size; (void)d_ws; (void)ws_size;

    unsigned char* heap = nullptr;
    hipGetSymbolAddress((void**)&heap, HIP_SYMBOL(g_heap));

    ushort* xin = (ushort*)(heap + OFF_XIN);
    ushort* xA  = (ushort*)(heap + OFF_XA);
    ushort* xB  = (ushort*)(heap + OFF_XB);
    ushort* y0  = (ushort*)(heap + OFF_Y0);
    ushort* y1  = (ushort*)(heap + OFF_Y1);
    ushort* y2  = (ushort*)(heap + OFF_Y2);
    ushort* whi = (ushort*)(heap + OFF_WHI);
    ushort* wlo = (ushort*)(heap + OFF_WLO);
    int* cc = (int*)(heap + OFF_CC);
    float* cv = (float*)(heap + OFF_CV);
    int* rp = (int*)(heap + OFF_RP);
    int* cnt = (int*)(heap + OFF_CNT);
    int* bsum = (int*)(heap + OFF_BS);
    int* bsum2 = (int*)(heap + OFF_BS2);
    float* pool = (float*)(heap + OFF_PL);
    float* Mbuf = (float*)(heap + OFF_M);

    const float* X0 = (const float*)d_in[0];
    const float* X1 = (const float*)d_in[1];
    const float* X2 = (const float*)d_in[2];
    const float* Wp = (const float*)d_in[29];

    // convert inputs to bf16 (padded segment bases)
    kcvt<<<dim3((cN0 * 32 + 255) / 256), 256, 0, stream>>>((const float4*)X0, (uint2*)xin, cN0 * 32);
    kcvt<<<dim3((cN1 * 32 + 255) / 256), 256, 0, stream>>>((const float4*)X1, (uint2*)(xin + (size_t)N0p * 128), cN1 * 32);
    kcvt<<<dim3((cN2 * 32 + 255) / 256), 256, 0, stream>>>((const float4*)X2, (uint2*)(xin + (size_t)(N0p + N1p) * 128), cN2 * 32);
    kwprep<<<dim3((NWE + 255) / 256), 256, 0, stream>>>(Wp, whi, wlo);

    // --- matrix descriptors ---
    static const int mnnz[13] = {800000, 800000, 800000, 1600000, 1600000, 1600000,
                                 800000, 800000, 800000, 400000, 400000, 300000, 300000};
    static const int mn[13] = {cN0, cN0, cN0, cN1, cN1, cN1, cN2, cN2, cN2, cN0, cN1, cN1, cN2};

    BDs bs;
    {
        int coff = 0, rpoff = 0, csroff = 0;
        for (int m = 0; m < 13; ++m) {
            BD& b = bs.d[m];
            if (m < 9) {
                const int* p = (const int*)d_in[3 + 2 * m];
                b.rows = p;
                b.cols = p + mnnz[m];
                b.vals = (const float*)d_in[4 + 2 * m];
            } else if (m == 9) { b.rows = (const int*)d_in[21]; b.cols = (const int*)d_in[22]; b.vals = (const float*)d_in[23]; }
            else if (m == 10) { b.rows = (const int*)d_in[22]; b.cols = (const int*)d_in[21]; b.vals = (const float*)d_in[23]; }
            else if (m == 11) { b.rows = (const int*)d_in[24]; b.cols = (const int*)d_in[25]; b.vals = (const float*)d_in[26]; }
            else              { b.rows = (const int*)d_in[25]; b.cols = (const int*)d_in[24]; b.vals = (const float*)d_in[26]; }
            b.nnz = mnnz[m]; b.n = mn[m];
            b.cnt_off = coff; b.rp_off = rpoff; b.csr_off = csroff;
            coff += mn[m]; rpoff += mn[m] + 1; csroff += mnnz[m];
        }
    }

    // --- CSR build ---
    kzero_i<<<dim3(2048), 256, 0, stream>>>(cnt, CNT_TOT);
    khist<<<dim3(1024, 13), 256, 0, stream>>>(bs, cnt);
    kscan1<<<dim3(196, 13), 1024, 0, stream>>>(bs, cnt, rp, bsum);
    kscan2<<<dim3(1, 13), 256, 0, stream>>>(bs, bsum, bsum2);
    kscan3<<<dim3(196, 13), 1024, 0, stream>>>(bs, rp, bsum2);
    kzero_i<<<dim3(2048), 256, 0, stream>>>(cnt, CNT_TOT);
    kscat<<<dim3(1024, 13), 256, 0, stream>>>(bs, rp, cnt, cc, cv);

    auto RP = [&](int m) { return rp + bs.d[m].rp_off; };
    auto CC = [&](int m) { return cc + bs.d[m].csr_off; };
    auto CV = [&](int m) { return cv + bs.d[m].csr_off; };

    constexpr int nb0 = N0p / 128, nb1 = N1p / 128, nb2 = N2p / 128;  // 782, 1563, 782

    for (int l = 0; l < 3; ++l) {
        const ushort* xi = (l == 0) ? xin : ((l == 1) ? xA : xB);
        ushort* xo = (l == 1) ? xB : xA;
        const ushort* x0p = xi;
        const ushort* x1p = xi + (size_t)N0p * 128;
        const ushort* x2p = xi + (size_t)(N0p + N1p) * 128;
        auto M_ = [&](int s, int t) { return (l * 3 + s) * 6 + t; };

        GGs gs{};
        int grid;
        if (l < 2) {
            gs.g[0] = {x0p, y0, cN0, nb0, 0,         640, 0, 5, {M_(0,0), M_(0,1), M_(0,2), M_(0,3), M_(1,4), 0}};
            gs.g[1] = {x1p, y1, cN1, nb1, nb0,       768, 0, 6, {M_(1,0), M_(1,1), M_(1,2), M_(1,3), M_(0,5), M_(2,4)}};
            gs.g[2] = {x2p, y2, cN2, nb2, nb0 + nb1, 640, 0, 5, {M_(2,0), M_(2,1), M_(2,2), M_(2,3), M_(1,5), 0}};
            gs.ng = 3; grid = nb0 + nb1 + nb2;
        } else {
            gs.g[0] = {x0p, y0, cN0, nb0, 0,   640, 0,   4, {M_(0,0), M_(0,1), M_(0,2), M_(0,3), 0, 0}};
            gs.g[1] = {x1p, y1, cN1, nb1, nb0, 768, 512, 1, {M_(0,5), 0, 0, 0, 0, 0}};
            gs.ng = 2; grid = nb0 + nb1;
        }
        kgemm_mfma<<<dim3(grid), 256, 0, stream>>>(gs, whi, wlo);

        // gather dim0
        {
            GA a{};
            a.nt = 4; a.ys = y0; a.sld = 640; a.soff = 0; a.out = xo; a.n = cN0;
            a.t[0] = {RP(0), CC(0), CV(0), y0, 640, 128};
            a.t[1] = {RP(1), CC(1), CV(1), y0, 640, 256};
            a.t[2] = {RP(2), CC(2), CV(2), y0, 640, 384};
            a.t[3] = {RP(9), CC(9), CV(9), y1, 768, 512};
            kgather<<<dim3((cN0 + 3) / 4), 256, 0, stream>>>(a);
        }
        if (l < 2) {
            GA a{};
            a.nt = 5; a.ys = y1; a.sld = 768; a.soff = 0; a.out = xo + (size_t)N0p * 128; a.n = cN1;
            a.t[0] = {RP(3), CC(3), CV(3), y1, 768, 128};
            a.t[1] = {RP(4), CC(4), CV(4), y1, 768, 256};
            a.t[2] = {RP(5), CC(5), CV(5), y1, 768, 384};
            a.t[3] = {RP(10), CC(10), CV(10), y0, 640, 512};
            a.t[4] = {RP(11), CC(11), CV(11), y2, 640, 512};
            kgather<<<dim3((cN1 + 3) / 4), 256, 0, stream>>>(a);

            GA a2{};
            a2.nt = 4; a2.ys = y2; a2.sld = 640; a2.soff = 0; a2.out = xo + (size_t)(N0p + N1p) * 128; a2.n = cN2;
            a2.t[0] = {RP(6), CC(6), CV(6), y2, 640, 128};
            a2.t[1] = {RP(7), CC(7), CV(7), y2, 640, 256};
            a2.t[2] = {RP(8), CC(8), CV(8), y2, 640, 384};
            a2.t[3] = {RP(12), CC(12), CV(12), y1, 768, 640};
            kgather<<<dim3((cN2 + 3) / 4), 256, 0, stream>>>(a2);
        }
    }

    // --- pooling + head ---
    kpool<<<dim3(cNHE), 128, 0, stream>>>(xA, (const int*)d_in[27], (const int*)d_in[28], pool);
    kmatm<<<dim3(8), 256, 0, stream>>>((const float*)d_in[30], (const float*)d_in[31], Mbuf);
    khead<<<dim3((cNHE - 1 + 15) / 16), 256, 0, stream>>>(pool, Mbuf, (const float*)d_in[32], (float*)d_out);
}

// Round 3
// 3065.257 us; speedup vs baseline: 2.1762x; 1.5386x over previous
//
#include <hip/hip_runtime.h>
#include <cstdint>
#include <cstddef>

typedef float f4v __attribute__((ext_vector_type(4)));
typedef __bf16 bf8 __attribute__((ext_vector_type(8)));

// ---------------- problem constants ----------------
constexpr int cN0 = 100000, cN1 = 200000, cN2 = 100000;
constexpr int cNHE = 20000, cHE = 200000;
constexpr int N0p = 100096, N1p = 200064, N2p = 100096;   // padded to 128 rows
constexpr int NTP = N0p + N1p + N2p;
constexpr int CNT_TOT = 1800000;     // sum of row counts over 13 matrices
constexpr int ELLW = 32;
constexpr int NWE = 54 * 16384;      // prepped W elements per plane

// ---------------- static device heap ----------------
constexpr size_t AL(size_t x) { return (x + 255) & ~(size_t)255; }
constexpr size_t OFF_XIN = 0;
constexpr size_t OFF_XA  = AL(OFF_XIN + (size_t)NTP * 128 * 2);
constexpr size_t OFF_XB  = AL(OFF_XA  + (size_t)NTP * 128 * 2);
constexpr size_t OFF_WHI = AL(OFF_XB  + (size_t)NTP * 128 * 2);
constexpr size_t OFF_WLO = AL(OFF_WHI + (size_t)NWE * 2);
constexpr size_t OFF_ELL = AL(OFF_WLO + (size_t)NWE * 2);
constexpr size_t OFF_CNT = AL(OFF_ELL + (size_t)CNT_TOT * ELLW * 8);
constexpr size_t OFF_PL  = AL(OFF_CNT + (size_t)CNT_TOT * 4);
constexpr size_t OFF_M   = AL(OFF_PL  + (size_t)cNHE * 128 * 4);
constexpr size_t HEAPSZ  = AL(OFF_M   + (size_t)128 * 16 * 4);

__device__ __align__(256) unsigned char g_heap[HEAPSZ];

// ---------------- helpers ----------------
__device__ __forceinline__ ushort f2bf(float f) {
    union { float f; uint32_t u; } v{f};
    uint32_t r = v.u + 0x7fffu + ((v.u >> 16) & 1u);
    return (ushort)(r >> 16);
}
__device__ __forceinline__ float bflo(uint32_t u) { union { uint32_t u; float f; } v{u << 16}; return v.f; }
__device__ __forceinline__ float bfhi(uint32_t u) { union { uint32_t u; float f; } v{u & 0xffff0000u}; return v.f; }

__device__ __forceinline__ void gl_lds16(const ushort* g, ushort* l) {
    __builtin_amdgcn_global_load_lds((const __attribute__((address_space(1))) void*)g,
                                     (__attribute__((address_space(3))) void*)l, 16, 0, 0);
}

__device__ __forceinline__ void acc16(float* a, uint4 lo, uint4 hi, float v) {
    a[0]  += v * bflo(lo.x); a[1]  += v * bfhi(lo.x);
    a[2]  += v * bflo(lo.y); a[3]  += v * bfhi(lo.y);
    a[4]  += v * bflo(lo.z); a[5]  += v * bfhi(lo.z);
    a[6]  += v * bflo(lo.w); a[7]  += v * bfhi(lo.w);
    a[8]  += v * bflo(hi.x); a[9]  += v * bfhi(hi.x);
    a[10] += v * bflo(hi.y); a[11] += v * bfhi(hi.y);
    a[12] += v * bflo(hi.z); a[13] += v * bfhi(hi.z);
    a[14] += v * bflo(hi.w); a[15] += v * bfhi(hi.w);
}

// ---------------- descriptor structs ----------------
struct BD { const int* rows; const int* cols; const float* vals; int nnz; int cnt_off; };
struct BDs { BD d[13]; };

struct FT { const ushort* xs; int cntb; int wm; };   // cntb = row base into cnt/ell (-1 => self term)
struct FG { ushort* xo; int n; int nblk; int bstart; int nt; FT t[6]; };
struct FGs { FG g[3]; int ng; };

// ---------------- utility kernels ----------------
__global__ void kzero_i(int* p, int n) {
    for (int i = blockIdx.x * 256 + threadIdx.x; i < n; i += gridDim.x * 256) p[i] = 0;
}

__global__ void kcvt(const float4* __restrict__ src, uint2* __restrict__ dst, int n4) {
    int i = blockIdx.x * 256 + threadIdx.x;
    if (i >= n4) return;
    float4 v = src[i];
    dst[i] = make_uint2((uint32_t)f2bf(v.x) | ((uint32_t)f2bf(v.y) << 16),
                        (uint32_t)f2bf(v.z) | ((uint32_t)f2bf(v.w) << 16));
}

// W prep: split into hi/lo bf16, arranged for direct 16B fragment loads.
// layout idx = ((kf*8+cf)*64 + lane)*8 + i  -> element (k = kf*32+(lane>>4)*8+i, c = cf*16+(lane&15))
__global__ void kwprep(const float* __restrict__ W, ushort* __restrict__ whi, ushort* __restrict__ wlo) {
    int t = blockIdx.x * 256 + threadIdx.x;
    if (t >= NWE) return;
    int mat = t >> 14, r = t & 16383;
    int i = r & 7, l = (r >> 3) & 63, cf = (r >> 9) & 7, kf = r >> 12;
    int k = kf * 32 + (l >> 4) * 8 + i;
    int c = cf * 16 + (l & 15);
    float w = W[(size_t)mat * 16384 + k * 128 + c];
    ushort h = f2bf(w);
    union { uint32_t u; float f; } hv{(uint32_t)h << 16};
    whi[t] = h;
    wlo[t] = f2bf(w - hv.f);
}

// ---------------- one-pass ELL build ----------------
__global__ void kscat_ell(BDs bs, int* cnt, uint2* ell) {
    BD b = bs.d[blockIdx.y];
    for (int e = blockIdx.x * 256 + threadIdx.x; e < b.nnz; e += gridDim.x * 256) {
        int r = b.rows[e];
        int pos = atomicAdd(&cnt[b.cnt_off + r], 1);
        if (pos < ELLW)
            ell[((size_t)(b.cnt_off + r) << 5) + pos] =
                make_uint2((uint32_t)b.cols[e], __float_as_uint(b.vals[e]));
    }
}

// ---------------- fused gather + MFMA GEMM + tanh ----------------
// out tile = tanh( sum_t (A_t . x_t)[128 rows] @ (Whi+Wlo)[wm_t] )
__global__ __launch_bounds__(256, 2) void kfused(FGs gs, const ushort* __restrict__ whi,
                                                 const ushort* __restrict__ wlo,
                                                 const int* __restrict__ cnt,
                                                 const uint2* __restrict__ ell) {
    __shared__ __align__(16) ushort xt[128 * 128];   // 32 KB: term-input staging, then output staging
    const int bx = blockIdx.x;
    int gi = 0;
#pragma unroll
    for (int i = 1; i < 3; ++i)
        if (i < gs.ng && bx >= gs.g[i].bstart) gi = i;
    const FG g = gs.g[gi];
    const int row0 = (bx - g.bstart) * 128;
    const int tid = threadIdx.x;
    const int lane = tid & 63, wv = tid >> 6;
    const int l15 = lane & 15, hi4 = lane >> 4;

    f4v acc[2][8];
    f4v zz = {0.f, 0.f, 0.f, 0.f};
#pragma unroll
    for (int rf = 0; rf < 2; ++rf)
#pragma unroll
        for (int cf = 0; cf < 8; ++cf) acc[rf][cf] = zz;

    for (int t = 0; t < g.nt; ++t) {
        const FT ft = g.t[t];
        if (ft.cntb < 0) {
            // self term: direct global->LDS, source pre-swizzled (chunk ^= row&7)
            const ushort* xb = ft.xs + (size_t)row0 * 128;
#pragma unroll
            for (int it = 0; it < 8; ++it) {
                int u = (it * 4 + wv) * 64 + lane;
                int r = u >> 4, c16 = u & 15;
                gl_lds16(xb + (size_t)r * 128 + ((c16 ^ (r & 7)) * 8), &xt[(it * 4 + wv) * 512]);
            }
        } else {
            // gather term: g = A.x, 8 threads/row x 16 cols, f32 accum -> bf16 -> swizzled LDS
#pragma unroll
            for (int p = 0; p < 4; ++p) {
                int r = p * 32 + (tid >> 3);
                int cs = tid & 7;
                int absr = row0 + r;
                float a[16];
#pragma unroll
                for (int j = 0; j < 16; ++j) a[j] = 0.f;
                const uint2* er = ell + ((size_t)(ft.cntb + absr) << 5);
                int deg = 0;
                if (absr < g.n) {
                    deg = cnt[ft.cntb + absr];
                    deg = deg > ELLW ? ELLW : deg;
                }
                const ushort* xsrc = ft.xs + cs * 16;
                int e = 0;
                for (; e + 2 <= deg; e += 2) {
                    uint4 rr = *(const uint4*)(er + e);     // two records
                    const ushort* p0 = xsrc + ((size_t)rr.x * 128);
                    const ushort* p1 = xsrc + ((size_t)rr.z * 128);
                    uint4 a0 = *(const uint4*)p0;
                    uint4 b0 = *(const uint4*)(p0 + 8);
                    uint4 a1 = *(const uint4*)p1;
                    uint4 b1 = *(const uint4*)(p1 + 8);
                    acc16(a, a0, b0, __uint_as_float(rr.y));
                    acc16(a, a1, b1, __uint_as_float(rr.w));
                }
                if (e < deg) {
                    uint2 rc = er[e];
                    const ushort* p0 = xsrc + ((size_t)rc.x * 128);
                    uint4 a0 = *(const uint4*)p0;
                    uint4 b0 = *(const uint4*)(p0 + 8);
                    acc16(a, a0, b0, __uint_as_float(rc.y));
                }
                uint32_t w[8];
#pragma unroll
                for (int j = 0; j < 8; ++j)
                    w[j] = (uint32_t)f2bf(a[2 * j]) | ((uint32_t)f2bf(a[2 * j + 1]) << 16);
                int c0 = (2 * cs) ^ (r & 7), c1 = (2 * cs + 1) ^ (r & 7);
                *(uint4*)&xt[r * 128 + c0 * 8] = make_uint4(w[0], w[1], w[2], w[3]);
                *(uint4*)&xt[r * 128 + c1 * 8] = make_uint4(w[4], w[5], w[6], w[7]);
            }
        }
        __syncthreads();

        // MFMA: acc += (W^T frag) x (g^T frag), hi + lo weight planes
        const int mat = ft.wm;
#pragma unroll
        for (int h = 0; h < 2; ++h) {
            const ushort* wb = (h ? wlo : whi) + (size_t)mat * 16384;
#pragma unroll
            for (int kf = 0; kf < 4; ++kf) {
                bf8 wf[8];
#pragma unroll
                for (int cf = 0; cf < 8; ++cf)
                    wf[cf] = *(const bf8*)(wb + ((kf * 8 + cf) * 64 + lane) * 8);
                bf8 xf[2];
#pragma unroll
                for (int rf = 0; rf < 2; ++rf) {
                    int rl = wv * 32 + rf * 16 + l15;
                    int slot = (kf * 4 + hi4) ^ (rl & 7);
                    xf[rf] = *(const bf8*)&xt[rl * 128 + slot * 8];
                }
#pragma unroll
                for (int rf = 0; rf < 2; ++rf)
#pragma unroll
                    for (int cf = 0; cf < 8; ++cf)
                        acc[rf][cf] = __builtin_amdgcn_mfma_f32_16x16x32_bf16(wf[cf], xf[rf], acc[rf][cf], 0, 0, 0);
            }
        }
        __syncthreads();   // xt reads done before next term overwrites
    }

    // epilogue: tanh -> bf16 -> swizzled LDS stage -> coalesced store
    ushort* sb = xt + wv * 4096;
#pragma unroll
    for (int rf = 0; rf < 2; ++rf) {
#pragma unroll
        for (int cf = 0; cf < 8; ++cf) {
            int rl = rf * 16 + l15;
            float t0 = tanhf(acc[rf][cf][0]), t1 = tanhf(acc[rf][cf][1]);
            float t2 = tanhf(acc[rf][cf][2]), t3 = tanhf(acc[rf][cf][3]);
            uint32_t p0 = (uint32_t)f2bf(t0) | ((uint32_t)f2bf(t1) << 16);
            uint32_t p1 = (uint32_t)f2bf(t2) | ((uint32_t)f2bf(t3) << 16);
            int s0 = cf * 2 + (hi4 >> 1);
            int byteoff = rl * 256 + ((s0 ^ (rl & 7)) * 16) + (hi4 & 1) * 8;
            *(uint2*)((char*)sb + byteoff) = make_uint2(p0, p1);
        }
    }
    __syncthreads();
    ushort* yb = g.xo + (size_t)(row0 + wv * 32) * 128;
#pragma unroll
    for (int it = 0; it < 8; ++it) {
        int rl = it * 4 + hi4;
        int s = l15 ^ (rl & 7);
        uint4 v = *(const uint4*)((const char*)sb + rl * 256 + s * 16);
        int absrow = row0 + wv * 32 + rl;
        if (absrow < g.n)
            *(uint4*)(yb + (size_t)rl * 128 + l15 * 8) = v;
    }
}

// ---------------- pooling + head ----------------
__device__ inline int lbound(const int* arr, int n, int key) {
    int lo = 0, hi = n;
    while (lo < hi) { int mid = (lo + hi) >> 1; if (arr[mid] < key) lo = mid + 1; else hi = mid; }
    return lo;
}

__global__ __launch_bounds__(128) void kpool(const ushort* x0, const int* he_idx, const int* he_seg, float* pool) {
    int s = blockIdx.x;
    int t = threadIdx.x;
    int lo = lbound(he_seg, cHE, s);
    int hi = lbound(he_seg, cHE, s + 1);
    float acc = 0.f;
    for (int e = lo; e < hi; ++e) acc += bflo((uint32_t)x0[(size_t)he_idx[e] * 128 + t]);
    float c = (float)(hi - lo);
    pool[(size_t)s * 128 + t] = acc / fmaxf(c, 1.f);
}

__global__ void kmatm(const float* Wfc, const float* Wcls, float* M) {
    int o = blockIdx.x * 256 + threadIdx.x;
    if (o >= 128 * 16) return;
    int dd = o >> 4, j = o & 15;
    float s = 0.f;
    for (int c = 0; c < 128; ++c) s += Wfc[dd * 128 + c] * Wcls[c * 16 + j];
    M[o] = s;
}

__global__ __launch_bounds__(256) void khead(const float* pool, const float* M, const float* bcls, float* out) {
    int row = blockIdx.x * 16 + (threadIdx.x >> 4);
    int j = threadIdx.x & 15;
    if (row >= cNHE - 1) return;
    int s = row + 1;
    float acc = bcls[j];
    const float* p = pool + (size_t)s * 128;
    for (int dd = 0; dd < 128; ++dd) acc += p[dd] * M[dd * 16 + j];
    out[(size_t)row * 16 + j] = acc;
}

// ---------------- host driver ----------------
extern "C" void kernel_launch(void* const* d_in, const int* in_sizes, int n_in,
                              void* d_out, int out_size, void* d_ws, size_t ws_size,
                              hipStream_t stream) {
    (void)in_sizes; (void)n_in; (void)out_size; (void)d_ws; (void)ws_size;

    unsigned char* heap = nullptr;
    hipGetSymbolAddress((void**)&heap, HIP_SYMBOL(g_heap));

    ushort* xin = (ushort*)(heap + OFF_XIN);
    ushort* xA  = (ushort*)(heap + OFF_XA);
    ushort* xB  = (ushort*)(heap + OFF_XB);
    ushort* whi = (ushort*)(heap + OFF_WHI);
    ushort* wlo = (ushort*)(heap + OFF_WLO);
    uint2* ell  = (uint2*)(heap + OFF_ELL);
    int* cnt    = (int*)(heap + OFF_CNT);
    float* pool = (float*)(heap + OFF_PL);
    float* Mbuf = (float*)(heap + OFF_M);

    const float* X0 = (const float*)d_in[0];
    const float* X1 = (const float*)d_in[1];
    const float* X2 = (const float*)d_in[2];
    const float* Wp = (const float*)d_in[29];

    // convert inputs to bf16 (padded segment bases)
    kcvt<<<dim3((cN0 * 32 + 255) / 256), 256, 0, stream>>>((const float4*)X0, (uint2*)xin, cN0 * 32);
    kcvt<<<dim3((cN1 * 32 + 255) / 256), 256, 0, stream>>>((const float4*)X1, (uint2*)(xin + (size_t)N0p * 128), cN1 * 32);
    kcvt<<<dim3((cN2 * 32 + 255) / 256), 256, 0, stream>>>((const float4*)X2, (uint2*)(xin + (size_t)(N0p + N1p) * 128), cN2 * 32);
    kwprep<<<dim3((NWE + 255) / 256), 256, 0, stream>>>(Wp, whi, wlo);

    // --- matrix descriptors (row-count bases into cnt/ell) ---
    static const int mnnz[13] = {800000, 800000, 800000, 1600000, 1600000, 1600000,
                                 800000, 800000, 800000, 400000, 400000, 300000, 300000};
    static const int mn[13] = {cN0, cN0, cN0, cN1, cN1, cN1, cN2, cN2, cN2, cN0, cN1, cN1, cN2};

    BDs bs;
    int cb[13];
    {
        int coff = 0;
        for (int m = 0; m < 13; ++m) {
            BD& b = bs.d[m];
            if (m < 9) {
                const int* p = (const int*)d_in[3 + 2 * m];
                b.rows = p;
                b.cols = p + mnnz[m];
                b.vals = (const float*)d_in[4 + 2 * m];
            } else if (m == 9) { b.rows = (const int*)d_in[21]; b.cols = (const int*)d_in[22]; b.vals = (const float*)d_in[23]; }
            else if (m == 10) { b.rows = (const int*)d_in[22]; b.cols = (const int*)d_in[21]; b.vals = (const float*)d_in[23]; }
            else if (m == 11) { b.rows = (const int*)d_in[24]; b.cols = (const int*)d_in[25]; b.vals = (const float*)d_in[26]; }
            else              { b.rows = (const int*)d_in[25]; b.cols = (const int*)d_in[24]; b.vals = (const float*)d_in[26]; }
            b.nnz = mnnz[m];
            b.cnt_off = coff;
            cb[m] = coff;
            coff += mn[m];
        }
    }

    // --- ELL build (one pass) ---
    kzero_i<<<dim3(2048), 256, 0, stream>>>(cnt, CNT_TOT);
    kscat_ell<<<dim3(1024, 13), 256, 0, stream>>>(bs, cnt, ell);

    constexpr int nb0 = N0p / 128, nb1 = N1p / 128, nb2 = N2p / 128;  // 782, 1563, 782

    for (int l = 0; l < 3; ++l) {
        const ushort* xi = (l == 0) ? xin : ((l == 1) ? xA : xB);
        ushort* xo = (l == 1) ? xB : xA;
        const ushort* x0p = xi;
        const ushort* x1p = xi + (size_t)N0p * 128;
        const ushort* x2p = xi + (size_t)(N0p + N1p) * 128;
        ushort* xo0 = xo;
        ushort* xo1 = xo + (size_t)N0p * 128;
        ushort* xo2 = xo + (size_t)(N0p + N1p) * 128;
        auto M_ = [&](int s, int t) { return (l * 3 + s) * 6 + t; };

        FGs fs{};
        int grid;
        if (l < 2) {
            fs.g[0] = {xo0, cN0, nb0, 0, 5,
                       {{x0p, -1, M_(0,0)}, {x0p, cb[0], M_(0,1)}, {x0p, cb[1], M_(0,2)},
                        {x0p, cb[2], M_(0,3)}, {x1p, cb[9], M_(0,5)}, {nullptr, 0, 0}}};
            fs.g[1] = {xo1, cN1, nb1, nb0, 6,
                       {{x1p, -1, M_(1,0)}, {x1p, cb[3], M_(1,1)}, {x1p, cb[4], M_(1,2)},
                        {x1p, cb[5], M_(1,3)}, {x0p, cb[10], M_(1,4)}, {x2p, cb[11], M_(1,5)}}};
            fs.g[2] = {xo2, cN2, nb2, nb0 + nb1, 5,
                       {{x2p, -1, M_(2,0)}, {x2p, cb[6], M_(2,1)}, {x2p, cb[7], M_(2,2)},
                        {x2p, cb[8], M_(2,3)}, {x1p, cb[12], M_(2,4)}, {nullptr, 0, 0}}};
            fs.ng = 3; grid = nb0 + nb1 + nb2;
        } else {
            fs.g[0] = {xo0, cN0, nb0, 0, 5,
                       {{x0p, -1, M_(0,0)}, {x0p, cb[0], M_(0,1)}, {x0p, cb[1], M_(0,2)},
                        {x0p, cb[2], M_(0,3)}, {x1p, cb[9], M_(0,5)}, {nullptr, 0, 0}}};
            fs.ng = 1; grid = nb0;
        }
        kfused<<<dim3(grid), 256, 0, stream>>>(fs, whi, wlo, cnt, ell);
    }

    // --- pooling + head ---
    kpool<<<dim3(cNHE), 128, 0, stream>>>(xA, (const int*)d_in[27], (const int*)d_in[28], pool);
    kmatm<<<dim3(8), 256, 0, stream>>>((const float*)d_in[30], (const float*)d_in[31], Mbuf);
    khead<<<dim3((cNHE - 1 + 15) / 16), 256, 0, stream>>>(pool, Mbuf, (const float*)d_in[32], (float*)d_out);
}